// Round 1
// baseline (689.863 us; speedup 1.0000x reference)
//
#include <hip/hip_runtime.h>
#include <hip/hip_bf16.h>
#include <math.h>

// Problem sizes (fixed by reference)
static constexpr int Bn = 16, Sn = 512, Wn = 8, Dn = 768;
static constexpr int Mn_ = 2, WMn = 64;
static constexpr int Un = 32, WUn = 16;

#define INF_VAL 1e12f

// Output float offsets
static constexpr size_t OFF_GCN   = 0;                    // [16,512,768]
static constexpr size_t OFF_MASK  = 6291456;              // [16,512,1]
static constexpr size_t OFF_DENSE = 6299648;              // [16,512,512]
static constexpr size_t OFF_ADJ   = 10493952;             // [16,512,512]
static constexpr size_t OFF_MAIN  = 14688256;             // [16,2,768]
static constexpr size_t OFF_USER  = 14712832;             // [16,768]

// Workspace float offsets
static constexpr size_t WS_G      = 0;                    // g [8192,768]
static constexpr size_t WS_QUERY  = 6291456;              // query [8192,768]
static constexpr size_t WS_COLSUM = 12582912;             // [16,512]

// ---------------------------------------------------------------------------
// g[b,s,d] = max_w (mask ? -INF : emb[word[b,s,w], d])   (no -INF fix)
// block = 192 threads (one float4 each), grid = B*S
__global__ __launch_bounds__(192)
void pool_g_kernel(const int* __restrict__ words, const int* __restrict__ masks,
                   const float* __restrict__ emb, float* __restrict__ g) {
    int bs = blockIdx.x;
    int t = threadIdx.x;
    const int* wrow = words + (size_t)bs * Wn;
    const int* mrow = masks + (size_t)bs * Wn;
    float4 acc = make_float4(-INF_VAL, -INF_VAL, -INF_VAL, -INF_VAL);
    #pragma unroll
    for (int w = 0; w < Wn; ++w) {
        if (mrow[w] != 0) continue;
        float4 v = ((const float4*)(emb + (size_t)wrow[w] * Dn))[t];
        acc.x = fmaxf(acc.x, v.x); acc.y = fmaxf(acc.y, v.y);
        acc.z = fmaxf(acc.z, v.z); acc.w = fmaxf(acc.w, v.w);
    }
    ((float4*)(g + (size_t)bs * Dn))[t] = acc;
}

// main_e: masked max over WM pieces, -INF -> 0. grid = B*M, block 192
__global__ __launch_bounds__(192)
void pool_main_kernel(const int* __restrict__ main_idx, const int* __restrict__ mmask,
                      const float* __restrict__ emb, float* __restrict__ out) {
    int bm = blockIdx.x;
    int t = threadIdx.x;
    const int* irow = main_idx + (size_t)bm * WMn;
    const int* mrow = mmask + (size_t)bm * WMn;
    float4 acc = make_float4(-INF_VAL, -INF_VAL, -INF_VAL, -INF_VAL);
    for (int w = 0; w < WMn; ++w) {
        if (mrow[w] != 0) continue;
        float4 v = ((const float4*)(emb + (size_t)irow[w] * Dn))[t];
        acc.x = fmaxf(acc.x, v.x); acc.y = fmaxf(acc.y, v.y);
        acc.z = fmaxf(acc.z, v.z); acc.w = fmaxf(acc.w, v.w);
    }
    if (acc.x == -INF_VAL) acc.x = 0.f;
    if (acc.y == -INF_VAL) acc.y = 0.f;
    if (acc.z == -INF_VAL) acc.z = 0.f;
    if (acc.w == -INF_VAL) acc.w = 0.f;
    ((float4*)(out + (size_t)bm * Dn))[t] = acc;
}

// user_e: max over all unmasked (u,wu), -INF -> 0. grid = B, block 192
__global__ __launch_bounds__(192)
void pool_user_kernel(const int* __restrict__ user_idx, const int* __restrict__ umask,
                      const float* __restrict__ emb, float* __restrict__ out) {
    int b = blockIdx.x;
    int t = threadIdx.x;
    __shared__ int sidx[Un * WUn];
    __shared__ int smask[Un * WUn];
    for (int i = t; i < Un * WUn; i += 192) {
        sidx[i]  = user_idx[(size_t)b * Un * WUn + i];
        smask[i] = umask[(size_t)b * Un * WUn + i];
    }
    __syncthreads();
    float4 acc = make_float4(-INF_VAL, -INF_VAL, -INF_VAL, -INF_VAL);
    for (int p = 0; p < Un * WUn; ++p) {
        if (smask[p] != 0) continue;
        float4 v = ((const float4*)(emb + (size_t)sidx[p] * Dn))[t];
        acc.x = fmaxf(acc.x, v.x); acc.y = fmaxf(acc.y, v.y);
        acc.z = fmaxf(acc.z, v.z); acc.w = fmaxf(acc.w, v.w);
    }
    if (acc.x == -INF_VAL) acc.x = 0.f;
    if (acc.y == -INF_VAL) acc.y = 0.f;
    if (acc.z == -INF_VAL) acc.z = 0.f;
    if (acc.w == -INF_VAL) acc.w = 0.f;
    ((float4*)(out + (size_t)b * Dn))[t] = acc;
}

// colsum[b,t] = sum_s adj[b,s,t]. grid = B, block 512
__global__ __launch_bounds__(512)
void colsum_kernel(const float* __restrict__ adj, float* __restrict__ colsum) {
    int b = blockIdx.x;
    int t = threadIdx.x;
    const float* base = adj + (size_t)b * Sn * Sn;
    float acc = 0.f;
    for (int s = 0; s < Sn; ++s) acc += base[(size_t)s * Sn + t];
    colsum[(size_t)b * Sn + t] = acc;
}

// adj softmax (exploits 0/1 entries) + node mask. grid = B*S, block 256
__global__ __launch_bounds__(256)
void adjsm_mask_kernel(const float* __restrict__ adj, const float* __restrict__ colsum,
                       float* __restrict__ adjsm, float* __restrict__ maskout) {
    int bs = blockIdx.x;
    int t = threadIdx.x;
    const float* row = adj + (size_t)bs * Sn;
    float a0 = row[t], a1 = row[t + 256];
    float local = a0 + a1;
    #pragma unroll
    for (int off = 32; off > 0; off >>= 1) local += __shfl_down(local, off, 64);
    __shared__ float red[4];
    __shared__ float bc;
    if ((t & 63) == 0) red[t >> 6] = local;
    __syncthreads();
    if (t == 0) {
        float n1 = red[0] + red[1] + red[2] + red[3];
        bc = n1;
        float cs = colsum[bs];
        maskout[bs] = ((n1 + cs) == 0.0f) ? 1.0f : 0.0f;
    }
    __syncthreads();
    float n1 = bc;
    float mx = (n1 > 0.f) ? 1.f : 0.f;
    float e1 = expf(1.f - mx);
    float e0 = expf(0.f - mx);
    float denom = n1 * e1 + (512.f - n1) * e0;
    float inv = 1.f / denom;
    float* outr = adjsm + (size_t)bs * Sn;
    outr[t]       = (a0 == 1.f ? e1 : e0) * inv;
    outr[t + 256] = (a1 == 1.f ? e1 : e0) * inv;
}

// ---------------------------------------------------------------------------
// Tiled f32 GEMM: C = alpha * A * op(B) + bias
// TRANSB=1: B is [N,K] (C=A*B^T), TRANSB=0: B is [K,N].
// 64x64 tile, BK=64, 256 threads, 4x4 micro-tile.
template<int TRANSB, int HASBIAS>
__global__ __launch_bounds__(256)
void gemm64(const float* __restrict__ A, const float* __restrict__ Bm,
            const float* __restrict__ bias, float* __restrict__ C,
            int Mm, int Nm, int Km, int lda, int ldb, int ldc,
            long long strideA, long long strideB, long long strideC, float alpha) {
    __shared__ float As[64][68];
    __shared__ float Bs[64][68];
    int bz = blockIdx.z;
    const float* Ab = A + (size_t)bz * strideA;
    const float* Bb = Bm + (size_t)bz * strideB;
    float* Cb = C + (size_t)bz * strideC;
    int i0 = blockIdx.y * 64, j0 = blockIdx.x * 64;
    int tid = threadIdx.x;
    int c = tid & 15, r = tid >> 4;
    float acc[4][4] = {};
    for (int k0 = 0; k0 < Km; k0 += 64) {
        // stage A transposed: As[kk][row]
        #pragma unroll
        for (int i = 0; i < 4; ++i) {
            int f = tid + i * 256;
            int row = f >> 4, kq = f & 15;
            float4 v = *(const float4*)(Ab + (size_t)(i0 + row) * lda + k0 + kq * 4);
            As[kq * 4 + 0][row] = v.x; As[kq * 4 + 1][row] = v.y;
            As[kq * 4 + 2][row] = v.z; As[kq * 4 + 3][row] = v.w;
        }
        if (TRANSB) {
            #pragma unroll
            for (int i = 0; i < 4; ++i) {
                int f = tid + i * 256;
                int col = f >> 4, kq = f & 15;
                float4 v = *(const float4*)(Bb + (size_t)(j0 + col) * ldb + k0 + kq * 4);
                Bs[kq * 4 + 0][col] = v.x; Bs[kq * 4 + 1][col] = v.y;
                Bs[kq * 4 + 2][col] = v.z; Bs[kq * 4 + 3][col] = v.w;
            }
        } else {
            #pragma unroll
            for (int i = 0; i < 4; ++i) {
                int f = tid + i * 256;
                int kk = f >> 4, cq = f & 15;
                float4 v = *(const float4*)(Bb + (size_t)(k0 + kk) * ldb + j0 + cq * 4);
                *(float4*)(&Bs[kk][cq * 4]) = v;
            }
        }
        __syncthreads();
        #pragma unroll 8
        for (int kk = 0; kk < 64; ++kk) {
            float4 a4 = *(const float4*)(&As[kk][r * 4]);
            float4 b4 = *(const float4*)(&Bs[kk][c * 4]);
            float av[4] = {a4.x, a4.y, a4.z, a4.w};
            float bv[4] = {b4.x, b4.y, b4.z, b4.w};
            #pragma unroll
            for (int rr = 0; rr < 4; ++rr)
                #pragma unroll
                for (int cc = 0; cc < 4; ++cc)
                    acc[rr][cc] = fmaf(av[rr], bv[cc], acc[rr][cc]);
        }
        __syncthreads();
    }
    float4 bv = make_float4(0.f, 0.f, 0.f, 0.f);
    if (HASBIAS) bv = *(const float4*)(bias + j0 + c * 4);
    #pragma unroll
    for (int rr = 0; rr < 4; ++rr) {
        float4 o;
        o.x = acc[rr][0] * alpha + bv.x;
        o.y = acc[rr][1] * alpha + bv.y;
        o.z = acc[rr][2] * alpha + bv.z;
        o.w = acc[rr][3] * alpha + bv.w;
        *(float4*)(Cb + (size_t)(i0 + r * 4 + rr) * ldc + j0 + c * 4) = o;
    }
}

// Row softmax over 512 entries in place. grid = B*S, block 256
__global__ __launch_bounds__(256)
void softmax512(float* __restrict__ data) {
    int row = blockIdx.x;
    float* p = data + (size_t)row * 512;
    int t = threadIdx.x;
    float x0 = p[t], x1 = p[t + 256];
    float m = fmaxf(x0, x1);
    #pragma unroll
    for (int off = 32; off > 0; off >>= 1) m = fmaxf(m, __shfl_down(m, off, 64));
    __shared__ float red[4];
    __shared__ float bmax, bsum;
    if ((t & 63) == 0) red[t >> 6] = m;
    __syncthreads();
    if (t == 0) bmax = fmaxf(fmaxf(red[0], red[1]), fmaxf(red[2], red[3]));
    __syncthreads();
    float mx = bmax;
    float e0 = expf(x0 - mx), e1 = expf(x1 - mx);
    float s = e0 + e1;
    #pragma unroll
    for (int off = 32; off > 0; off >>= 1) s += __shfl_down(s, off, 64);
    if ((t & 63) == 0) red[t >> 6] = s;
    __syncthreads();
    if (t == 0) bsum = red[0] + red[1] + red[2] + red[3];
    __syncthreads();
    float inv = 1.f / bsum;
    p[t] = e0 * inv;
    p[t + 256] = e1 * inv;
}

// ---------------------------------------------------------------------------
extern "C" void kernel_launch(void* const* d_in, const int* in_sizes, int n_in,
                              void* d_out, int out_size, void* d_ws, size_t ws_size,
                              hipStream_t stream) {
    const int*   words     = (const int*)d_in[0];
    const int*   masks     = (const int*)d_in[1];
    const int*   main_idx  = (const int*)d_in[2];
    const int*   main_mask = (const int*)d_in[3];
    const int*   user_idx  = (const int*)d_in[4];
    const int*   user_mask = (const int*)d_in[5];
    const float* adj       = (const float*)d_in[6];
    const float* emb       = (const float*)d_in[7];
    const float* K_w       = (const float*)d_in[8];
    const float* K_b       = (const float*)d_in[9];
    const float* Q_w       = (const float*)d_in[10];
    const float* Q_b       = (const float*)d_in[11];

    float* out = (float*)d_out;
    float* ws  = (float*)d_ws;

    float* g      = ws + WS_G;
    float* query  = ws + WS_QUERY;
    float* colsum = ws + WS_COLSUM;
    float* key    = out + OFF_GCN;     // temp; overwritten by gcn_out at the end
    float* dense  = out + OFF_DENSE;

    // pools
    pool_g_kernel<<<Bn * Sn, 192, 0, stream>>>(words, masks, emb, g);
    pool_main_kernel<<<Bn * Mn_, 192, 0, stream>>>(main_idx, main_mask, emb, out + OFF_MAIN);
    pool_user_kernel<<<Bn, 192, 0, stream>>>(user_idx, user_mask, emb, out + OFF_USER);

    // adjacency: colsums, then softmax + node mask
    colsum_kernel<<<Bn, 512, 0, stream>>>(adj, colsum);
    adjsm_mask_kernel<<<Bn * Sn, 256, 0, stream>>>(adj, colsum, out + OFF_ADJ, out + OFF_MASK);

    // key = g @ K_w^T + K_b   -> gcn region (temp)
    gemm64<1, 1><<<dim3(Dn / 64, (Bn * Sn) / 64, 1), 256, 0, stream>>>(
        g, K_w, K_b, key, Bn * Sn, Dn, Dn, Dn, Dn, Dn, 0, 0, 0, 1.0f);
    // query = g @ Q_w^T + Q_b -> ws
    gemm64<1, 1><<<dim3(Dn / 64, (Bn * Sn) / 64, 1), 256, 0, stream>>>(
        g, Q_w, Q_b, query, Bn * Sn, Dn, Dn, Dn, Dn, Dn, 0, 0, 0, 1.0f);

    // scores[b] = key[b] @ query[b]^T / sqrt(D) -> dense region
    float inv_sqrt_d = (float)(1.0 / sqrt((double)Dn));
    gemm64<1, 0><<<dim3(Sn / 64, Sn / 64, Bn), 256, 0, stream>>>(
        key, query, nullptr, dense, Sn, Sn, Dn, Dn, Dn, Sn,
        (long long)Sn * Dn, (long long)Sn * Dn, (long long)Sn * Sn, inv_sqrt_d);

    // softmax rows of dense
    softmax512<<<Bn * Sn, 256, 0, stream>>>(dense);

    // gcn_out[b] = P[b] @ g[b] -> gcn region (overwrites key)
    gemm64<0, 0><<<dim3(Dn / 64, Sn / 64, Bn), 256, 0, stream>>>(
        dense, g, nullptr, out + OFF_GCN, Sn, Dn, Sn, Sn, Dn, Dn,
        (long long)Sn * Sn, (long long)Sn * Dn, (long long)Sn * Dn, 1.0f);
}

// Round 2
// 368.191 us; speedup vs baseline: 1.8737x; 1.8737x over previous
//
#include <hip/hip_runtime.h>
#include <hip/hip_bf16.h>
#include <math.h>

// Problem sizes (fixed by reference)
static constexpr int Bn = 16, Sn = 512, Wn = 8, Dn = 768;
static constexpr int Mn_ = 2, WMn = 64;
static constexpr int Un = 32, WUn = 16;

#define INF_VAL 1e12f
#define INV_SQRT_D 0.03608439182435161f

// Output float offsets
static constexpr size_t OFF_GCN   = 0;                    // [16,512,768]
static constexpr size_t OFF_MASK  = 6291456;              // [16,512,1]
static constexpr size_t OFF_DENSE = 6299648;              // [16,512,512]
static constexpr size_t OFF_ADJ   = 10493952;             // [16,512,512]
static constexpr size_t OFF_MAIN  = 14688256;             // [16,2,768]
static constexpr size_t OFF_USER  = 14712832;             // [16,768]

// Workspace byte offsets
static constexpr size_t WSB_GBF    = 0;          // g bf16 [8192][768]      12582912 B
static constexpr size_t WSB_GT     = 12582912;   // gT bf16 [16][768][512]  12582912 B
static constexpr size_t WSB_KBAR   = 25165824;   // double[768]
static constexpr size_t WSB_QBAR   = 25171968;   // double[768]
static constexpr size_t WSB_U      = 25178112;   // double[768]
static constexpr size_t WSB_V      = 25184256;   // double[768]
static constexpr size_t WSB_CONSTS = 25190400;   // double[4]: c0,c1,c2
static constexpr size_t WSB_QS     = 25190464;   // float[8192]
static constexpr size_t WSB_KQ     = 25223232;   // float[8192]
static constexpr size_t WSB_COLSUM = 25256000;   // float[8192]
static constexpr size_t WSB_FLAGS  = 25288768;   // int[8192]

typedef __attribute__((ext_vector_type(8))) short short8;
typedef __attribute__((ext_vector_type(4))) float f32x4;

static __device__ __forceinline__ ushort f2bf(float f) {
    union { float f; unsigned u; } v; v.f = f;
    unsigned u = v.u;
    unsigned r = (u + 0x7FFFu + ((u >> 16) & 1u)) >> 16;
    return (ushort)r;
}

static __device__ __forceinline__ void gload16(const void* g, void* lds) {
    __builtin_amdgcn_global_load_lds(
        (const __attribute__((address_space(1))) void*)g,
        (__attribute__((address_space(3))) void*)lds, 16, 0, 0);
}

// ---------------------------------------------------------------------------
// Weight-fold kernels (all weight-only, batch independent; f64 for argmax fidelity)
// kbar_e = -1e12*sum_d K_w[e,d] + K_b[e]; qbar likewise.
__global__ __launch_bounds__(64)
void bar_kernel(const float* __restrict__ K_w, const float* __restrict__ K_b,
                const float* __restrict__ Q_w, const float* __restrict__ Q_b,
                double* __restrict__ kbar, double* __restrict__ qbar) {
    int e = blockIdx.x;
    int l = threadIdx.x;
    double sk = 0.0, sq = 0.0;
    for (int d = l; d < Dn; d += 64) {
        sk += (double)K_w[(size_t)e * Dn + d];
        sq += (double)Q_w[(size_t)e * Dn + d];
    }
    #pragma unroll
    for (int off = 32; off > 0; off >>= 1) {
        sk += __shfl_down(sk, off, 64);
        sq += __shfl_down(sq, off, 64);
    }
    if (l == 0) {
        kbar[e] = -1e12 * sk + (double)K_b[e];
        qbar[e] = -1e12 * sq + (double)Q_b[e];
    }
}

// u_j = sum_e K_w[e,j]*qbar_e ; v_j = sum_e Q_w[e,j]*kbar_e
__global__ __launch_bounds__(128)
void uv_kernel(const float* __restrict__ K_w, const float* __restrict__ Q_w,
               const double* __restrict__ kbar, const double* __restrict__ qbar,
               double* __restrict__ u, double* __restrict__ v) {
    int j = blockIdx.x * 128 + threadIdx.x;
    double su = 0.0, sv = 0.0;
    for (int e = 0; e < Dn; ++e) {
        su += (double)K_w[(size_t)e * Dn + j] * qbar[e];
        sv += (double)Q_w[(size_t)e * Dn + j] * kbar[e];
    }
    u[j] = su; v[j] = sv;
}

// c0 = kbar.Q_b ; c1 = kbar.qbar ; c2 = qbar.K_b
__global__ __launch_bounds__(64)
void consts_kernel(const double* __restrict__ kbar, const double* __restrict__ qbar,
                   const float* __restrict__ K_b, const float* __restrict__ Q_b,
                   double* __restrict__ consts) {
    int l = threadIdx.x;
    double c0 = 0.0, c1 = 0.0, c2 = 0.0;
    for (int e = l; e < Dn; e += 64) {
        c0 += kbar[e] * (double)Q_b[e];
        c1 += kbar[e] * qbar[e];
        c2 += qbar[e] * (double)K_b[e];
    }
    #pragma unroll
    for (int off = 32; off > 0; off >>= 1) {
        c0 += __shfl_down(c0, off, 64);
        c1 += __shfl_down(c1, off, 64);
        c2 += __shfl_down(c2, off, 64);
    }
    if (l == 0) { consts[0] = c0; consts[1] = c1; consts[2] = c2; }
}

// f32 -> bf16 bulk convert
__global__ __launch_bounds__(256)
void cvt_bf16(const float* __restrict__ in, ushort* __restrict__ out, int n) {
    int i = blockIdx.x * 256 + threadIdx.x;
    if (i * 4 < n) {
        float4 v = ((const float4*)in)[i];
        ushort4 o;
        o.x = f2bf(v.x); o.y = f2bf(v.y); o.z = f2bf(v.z); o.w = f2bf(v.w);
        ((ushort4*)out)[i] = o;
    }
}

// ---------------------------------------------------------------------------
// g pool: bf16 g + exact f32-row dots qs/kq (f64 accum) + row-masked flag.
__global__ __launch_bounds__(192)
void pool_g_kernel(const int* __restrict__ words, const int* __restrict__ masks,
                   const float* __restrict__ emb,
                   const double* __restrict__ u, const double* __restrict__ v,
                   const double* __restrict__ consts,
                   ushort* __restrict__ gbf, float* __restrict__ qs,
                   float* __restrict__ kq, int* __restrict__ flags) {
    int bs = blockIdx.x;
    int t = threadIdx.x;
    const int* wrow = words + (size_t)bs * Wn;
    const int* mrow = masks + (size_t)bs * Wn;
    float4 acc = make_float4(-INF_VAL, -INF_VAL, -INF_VAL, -INF_VAL);
    int nm = 0;
    #pragma unroll
    for (int w = 0; w < Wn; ++w) {
        int mk = mrow[w];
        nm += (mk != 0);
        if (mk != 0) continue;
        float4 x = ((const float4*)(emb + (size_t)wrow[w] * Dn))[t];
        acc.x = fmaxf(acc.x, x.x); acc.y = fmaxf(acc.y, x.y);
        acc.z = fmaxf(acc.z, x.z); acc.w = fmaxf(acc.w, x.w);
    }
    ushort4 o;
    o.x = f2bf(acc.x); o.y = f2bf(acc.y); o.z = f2bf(acc.z); o.w = f2bf(acc.w);
    ((ushort4*)(gbf + (size_t)bs * Dn))[t] = o;
    // exact dots with fold vectors (f64)
    int j = t * 4;
    double dv = v[j] * (double)acc.x + v[j+1] * (double)acc.y
              + v[j+2] * (double)acc.z + v[j+3] * (double)acc.w;
    double du = u[j] * (double)acc.x + u[j+1] * (double)acc.y
              + u[j+2] * (double)acc.z + u[j+3] * (double)acc.w;
    #pragma unroll
    for (int off = 32; off > 0; off >>= 1) {
        dv += __shfl_down(dv, off, 64);
        du += __shfl_down(du, off, 64);
    }
    __shared__ double rr[6];
    if ((t & 63) == 0) { rr[t >> 6] = dv; rr[3 + (t >> 6)] = du; }
    __syncthreads();
    if (t == 0) {
        qs[bs] = (float)(rr[0] + rr[1] + rr[2] + consts[0]);
        kq[bs] = (float)(rr[3] + rr[4] + rr[5] + consts[2]);
        flags[bs] = (nm == Wn) ? 1 : 0;
    }
}

// main_e: masked max over WM pieces, -INF -> 0. grid = B*M, block 192
__global__ __launch_bounds__(192)
void pool_main_kernel(const int* __restrict__ main_idx, const int* __restrict__ mmask,
                      const float* __restrict__ emb, float* __restrict__ out) {
    int bm = blockIdx.x;
    int t = threadIdx.x;
    const int* irow = main_idx + (size_t)bm * WMn;
    const int* mrow = mmask + (size_t)bm * WMn;
    float4 acc = make_float4(-INF_VAL, -INF_VAL, -INF_VAL, -INF_VAL);
    for (int w = 0; w < WMn; ++w) {
        if (mrow[w] != 0) continue;
        float4 x = ((const float4*)(emb + (size_t)irow[w] * Dn))[t];
        acc.x = fmaxf(acc.x, x.x); acc.y = fmaxf(acc.y, x.y);
        acc.z = fmaxf(acc.z, x.z); acc.w = fmaxf(acc.w, x.w);
    }
    if (acc.x == -INF_VAL) acc.x = 0.f;
    if (acc.y == -INF_VAL) acc.y = 0.f;
    if (acc.z == -INF_VAL) acc.z = 0.f;
    if (acc.w == -INF_VAL) acc.w = 0.f;
    ((float4*)(out + (size_t)bm * Dn))[t] = acc;
}

__global__ __launch_bounds__(192)
void pool_user_kernel(const int* __restrict__ user_idx, const int* __restrict__ umask,
                      const float* __restrict__ emb, float* __restrict__ out) {
    int b = blockIdx.x;
    int t = threadIdx.x;
    __shared__ int sidx[Un * WUn];
    __shared__ int smask[Un * WUn];
    for (int i = t; i < Un * WUn; i += 192) {
        sidx[i]  = user_idx[(size_t)b * Un * WUn + i];
        smask[i] = umask[(size_t)b * Un * WUn + i];
    }
    __syncthreads();
    float4 acc = make_float4(-INF_VAL, -INF_VAL, -INF_VAL, -INF_VAL);
    for (int p = 0; p < Un * WUn; ++p) {
        if (smask[p] != 0) continue;
        float4 x = ((const float4*)(emb + (size_t)sidx[p] * Dn))[t];
        acc.x = fmaxf(acc.x, x.x); acc.y = fmaxf(acc.y, x.y);
        acc.z = fmaxf(acc.z, x.z); acc.w = fmaxf(acc.w, x.w);
    }
    if (acc.x == -INF_VAL) acc.x = 0.f;
    if (acc.y == -INF_VAL) acc.y = 0.f;
    if (acc.z == -INF_VAL) acc.z = 0.f;
    if (acc.w == -INF_VAL) acc.w = 0.f;
    ((float4*)(out + (size_t)b * Dn))[t] = acc;
}

// colsum[b,t] = sum_s adj[b,s,t]
__global__ __launch_bounds__(512)
void colsum_kernel(const float* __restrict__ adj, float* __restrict__ colsum) {
    int b = blockIdx.x;
    int t = threadIdx.x;
    const float* base = adj + (size_t)b * Sn * Sn;
    float acc = 0.f;
    for (int s = 0; s < Sn; ++s) acc += base[(size_t)s * Sn + t];
    colsum[(size_t)b * Sn + t] = acc;
}

// adj softmax (0/1 entries) + node mask
__global__ __launch_bounds__(256)
void adjsm_mask_kernel(const float* __restrict__ adj, const float* __restrict__ colsum,
                       float* __restrict__ adjsm, float* __restrict__ maskout) {
    int bs = blockIdx.x;
    int t = threadIdx.x;
    const float* row = adj + (size_t)bs * Sn;
    float a0 = row[t], a1 = row[t + 256];
    float local = a0 + a1;
    #pragma unroll
    for (int off = 32; off > 0; off >>= 1) local += __shfl_down(local, off, 64);
    __shared__ float red[4];
    __shared__ float bc;
    if ((t & 63) == 0) red[t >> 6] = local;
    __syncthreads();
    if (t == 0) {
        float n1 = red[0] + red[1] + red[2] + red[3];
        bc = n1;
        float cs = colsum[bs];
        maskout[bs] = ((n1 + cs) == 0.0f) ? 1.0f : 0.0f;
    }
    __syncthreads();
    float n1 = bc;
    float mx = (n1 > 0.f) ? 1.f : 0.f;
    float e1 = expf(1.f - mx);
    float e0 = expf(0.f - mx);
    float denom = n1 * e1 + (512.f - n1) * e0;
    float inv = 1.f / denom;
    float* outr = adjsm + (size_t)bs * Sn;
    outr[t]       = (a0 == 1.f ? e1 : e0) * inv;
    outr[t + 256] = (a1 == 1.f ? e1 : e0) * inv;
}

// transpose bf16 g -> gT[b][d][s]
__global__ __launch_bounds__(256)
void transpose_g(const ushort* __restrict__ gbf, ushort* __restrict__ gT) {
    __shared__ ushort tile[32][33];
    int b = blockIdx.z;
    int d0 = blockIdx.x * 32, s0 = blockIdx.y * 32;
    int tx = threadIdx.x & 31, ty = threadIdx.x >> 5;
    #pragma unroll
    for (int i = 0; i < 4; ++i)
        tile[ty + i * 8][tx] = gbf[((size_t)(b * Sn + s0 + ty + i * 8)) * Dn + d0 + tx];
    __syncthreads();
    #pragma unroll
    for (int i = 0; i < 4; ++i)
        gT[((size_t)(b * Dn + d0 + ty + i * 8)) * Sn + s0 + tx] = tile[tx][ty + i * 8];
}

// ---------------------------------------------------------------------------
// bf16 MFMA GEMM: C[m][n] = sum_k A[m][k]*B[n][k] (+bias[n])
// 128x128 tile, BK=64, 256 threads = 4 waves (2x2), 16x16x32 MFMA.
// LDS tiles [row][64k] bf16 (128B rows), XOR chunk-swizzle ((row&7) on 16B chunks)
// applied on BOTH the global staging source and the ds_read address.
template<int OUT_BF16, int HASBIAS>
__global__ __launch_bounds__(256)
void gemm_mfma(const ushort* __restrict__ A, const ushort* __restrict__ B,
               const float* __restrict__ bias, void* __restrict__ Cout,
               int Km, int lda, int ldb, int ldc,
               long long sA, long long sB, long long sC) {
    __shared__ ushort As[128 * 64];
    __shared__ ushort Bs[128 * 64];
    const ushort* Ab = A + (size_t)blockIdx.z * sA;
    const ushort* Bb = B + (size_t)blockIdx.z * sB;
    int i0 = blockIdx.y * 128, j0 = blockIdx.x * 128;
    int tid = threadIdx.x;
    int lane = tid & 63, wv = tid >> 6;
    int wr = wv >> 1, wc = wv & 1;
    int ln15 = lane & 15, lkg = lane >> 4;
    int sub = lane >> 3;        // 0..7
    int c8  = lane & 7;         // 16B chunk index

    f32x4 acc[4][4] = {};

    for (int k0 = 0; k0 < Km; k0 += 64) {
        #pragma unroll
        for (int it = 0; it < 4; ++it) {
            int r = it * 32 + wv * 8 + sub;
            int cc = c8 ^ (r & 7);
            ushort* dstA = As + (it * 4096 + wv * 1024) / 2;  // wave-uniform
            ushort* dstB = Bs + (it * 4096 + wv * 1024) / 2;
            gload16(Ab + (size_t)(i0 + r) * lda + k0 + cc * 8, dstA);
            gload16(Bb + (size_t)(j0 + r) * ldb + k0 + cc * 8, dstB);
        }
        __syncthreads();
        #pragma unroll
        for (int kh = 0; kh < 2; ++kh) {
            short8 af[4], bfr[4];
            int kc = kh * 4 + lkg;
            #pragma unroll
            for (int f = 0; f < 4; ++f) {
                int ra = wr * 64 + f * 16 + ln15;
                af[f] = *(const short8*)((const char*)As + ra * 128 + ((kc ^ (ra & 7)) << 4));
                int rb = wc * 64 + f * 16 + ln15;
                bfr[f] = *(const short8*)((const char*)Bs + rb * 128 + ((kc ^ (rb & 7)) << 4));
            }
            #pragma unroll
            for (int fa = 0; fa < 4; ++fa)
                #pragma unroll
                for (int fb = 0; fb < 4; ++fb)
                    acc[fa][fb] = __builtin_amdgcn_mfma_f32_16x16x32_bf16(
                        af[fa], bfr[fb], acc[fa][fb], 0, 0, 0);
        }
        __syncthreads();
    }

    // epilogue: D row = (lane>>4)*4 + r, col = lane&15 within each 16x16 frag
    #pragma unroll
    for (int fa = 0; fa < 4; ++fa) {
        #pragma unroll
        for (int fb = 0; fb < 4; ++fb) {
            int n = j0 + wc * 64 + fb * 16 + ln15;
            float bv = HASBIAS ? bias[n] : 0.0f;
            #pragma unroll
            for (int rr = 0; rr < 4; ++rr) {
                int m = i0 + wr * 64 + fa * 16 + lkg * 4 + rr;
                float val = acc[fa][fb][rr] + bv;
                if (OUT_BF16) {
                    ((ushort*)Cout)[(size_t)blockIdx.z * sC + (size_t)m * ldc + n] = f2bf(val);
                } else {
                    ((float*)Cout)[(size_t)blockIdx.z * sC + (size_t)m * ldc + n] = val;
                }
            }
        }
    }
}

// ---------------------------------------------------------------------------
// scores fixup + row softmax. Overrides masked rows/cols with exact rank-1 values.
__global__ __launch_bounds__(256)
void softmax_fix(float* __restrict__ dense, const int* __restrict__ flags,
                 const float* __restrict__ qs, const float* __restrict__ kq,
                 const double* __restrict__ consts, ushort* __restrict__ densebf) {
    int bs = blockIdx.x;
    int b = bs >> 9;
    int t = threadIdx.x;
    float* row = dense + (size_t)bs * 512;
    int f0 = flags[(b << 9) + t];
    int f1 = flags[(b << 9) + t + 256];
    bool sm = flags[bs] != 0;
    float x0, x1;
    if (sm) {
        float c1i = (float)consts[1] * INV_SQRT_D;
        x0 = f0 ? c1i : qs[(b << 9) + t] * INV_SQRT_D;
        x1 = f1 ? c1i : qs[(b << 9) + t + 256] * INV_SQRT_D;
    } else {
        float kqi = kq[bs] * INV_SQRT_D;
        x0 = f0 ? kqi : row[t] * INV_SQRT_D;
        x1 = f1 ? kqi : row[t + 256] * INV_SQRT_D;
    }
    float m = fmaxf(x0, x1);
    #pragma unroll
    for (int off = 32; off > 0; off >>= 1) m = fmaxf(m, __shfl_down(m, off, 64));
    __shared__ float red[4];
    __shared__ float bmax, bsum;
    if ((t & 63) == 0) red[t >> 6] = m;
    __syncthreads();
    if (t == 0) bmax = fmaxf(fmaxf(red[0], red[1]), fmaxf(red[2], red[3]));
    __syncthreads();
    float mx = bmax;
    float e0 = expf(x0 - mx), e1 = expf(x1 - mx);
    float s = e0 + e1;
    #pragma unroll
    for (int off = 32; off > 0; off >>= 1) s += __shfl_down(s, off, 64);
    if ((t & 63) == 0) red[t >> 6] = s;
    __syncthreads();
    if (t == 0) bsum = red[0] + red[1] + red[2] + red[3];
    __syncthreads();
    float inv = 1.f / bsum;
    float p0 = e0 * inv, p1 = e1 * inv;
    row[t] = p0; row[t + 256] = p1;
    ushort* bro = densebf + (size_t)bs * 512;
    bro[t] = f2bf(p0); bro[t + 256] = f2bf(p1);
}

// ---------------------------------------------------------------------------
extern "C" void kernel_launch(void* const* d_in, const int* in_sizes, int n_in,
                              void* d_out, int out_size, void* d_ws, size_t ws_size,
                              hipStream_t stream) {
    const int*   words     = (const int*)d_in[0];
    const int*   masks     = (const int*)d_in[1];
    const int*   main_idx  = (const int*)d_in[2];
    const int*   main_mask = (const int*)d_in[3];
    const int*   user_idx  = (const int*)d_in[4];
    const int*   user_mask = (const int*)d_in[5];
    const float* adj       = (const float*)d_in[6];
    const float* emb       = (const float*)d_in[7];
    const float* K_w       = (const float*)d_in[8];
    const float* K_b       = (const float*)d_in[9];
    const float* Q_w       = (const float*)d_in[10];
    const float* Q_b       = (const float*)d_in[11];

    float* out = (float*)d_out;
    char*  ws8 = (char*)d_ws;

    ushort* gbf    = (ushort*)(ws8 + WSB_GBF);
    ushort* gT     = (ushort*)(ws8 + WSB_GT);
    double* kbar   = (double*)(ws8 + WSB_KBAR);
    double* qbar   = (double*)(ws8 + WSB_QBAR);
    double* u      = (double*)(ws8 + WSB_U);
    double* v      = (double*)(ws8 + WSB_V);
    double* consts = (double*)(ws8 + WSB_CONSTS);
    float*  qs     = (float*)(ws8 + WSB_QS);
    float*  kq     = (float*)(ws8 + WSB_KQ);
    float*  colsum = (float*)(ws8 + WSB_COLSUM);
    int*    flags  = (int*)(ws8 + WSB_FLAGS);

    // scratch parked in output regions (all fully rewritten later each call)
    ushort* Kwb     = (ushort*)(out + OFF_DENSE);              // dead before scores GEMM
    ushort* Qwb     = Kwb + (size_t)Dn * Dn;
    ushort* keybf   = (ushort*)(out + OFF_GCN);                // dead before gcn GEMM
    ushort* querybf = keybf + (size_t)Bn * Sn * Dn;
    float*  dense   = out + OFF_DENSE;
    ushort* densebf = (ushort*)(out + OFF_ADJ);                // dead before adjsm

    // weight folds (batch-independent)
    bar_kernel<<<Dn, 64, 0, stream>>>(K_w, K_b, Q_w, Q_b, kbar, qbar);
    uv_kernel<<<Dn / 128, 128, 0, stream>>>(K_w, Q_w, kbar, qbar, u, v);
    consts_kernel<<<1, 64, 0, stream>>>(kbar, qbar, K_b, Q_b, consts);
    cvt_bf16<<<(Dn * Dn / 4 + 255) / 256, 256, 0, stream>>>(K_w, Kwb, Dn * Dn);
    cvt_bf16<<<(Dn * Dn / 4 + 255) / 256, 256, 0, stream>>>(Q_w, Qwb, Dn * Dn);

    // pools
    pool_g_kernel<<<Bn * Sn, 192, 0, stream>>>(words, masks, emb, u, v, consts,
                                               gbf, qs, kq, flags);
    pool_main_kernel<<<Bn * Mn_, 192, 0, stream>>>(main_idx, main_mask, emb, out + OFF_MAIN);
    pool_user_kernel<<<Bn, 192, 0, stream>>>(user_idx, user_mask, emb, out + OFF_USER);
    colsum_kernel<<<Bn, 512, 0, stream>>>(adj, colsum);
    transpose_g<<<dim3(Dn / 32, Sn / 32, Bn), 256, 0, stream>>>(gbf, gT);

    // key = g @ K_w^T + K_b (bf16 out) ; query likewise
    gemm_mfma<1, 1><<<dim3(Dn / 128, (Bn * Sn) / 128, 1), 256, 0, stream>>>(
        gbf, Kwb, K_b, keybf, Dn, Dn, Dn, Dn, 0, 0, 0);
    gemm_mfma<1, 1><<<dim3(Dn / 128, (Bn * Sn) / 128, 1), 256, 0, stream>>>(
        gbf, Qwb, Q_b, querybf, Dn, Dn, Dn, Dn, 0, 0, 0);

    // raw scores[b] = key[b] @ query[b]^T (f32 out, scale applied in softmax)
    gemm_mfma<0, 0><<<dim3(Sn / 128, Sn / 128, Bn), 256, 0, stream>>>(
        keybf, querybf, nullptr, dense, Dn, Dn, Dn, Sn,
        (long long)Sn * Dn, (long long)Sn * Dn, (long long)Sn * Sn);

    // fixup masked rows/cols + softmax; writes f32 dense + bf16 copy
    softmax_fix<<<Bn * Sn, 256, 0, stream>>>(dense, flags, qs, kq, consts, densebf);

    // gcn[b] = P[b] @ g[b] = densebf @ gT^T (f32 out)
    gemm_mfma<0, 0><<<dim3(Dn / 128, Sn / 128, Bn), 256, 0, stream>>>(
        densebf, gT, nullptr, out + OFF_GCN, Sn, Sn, Sn, Dn,
        (long long)Sn * Sn, (long long)Dn * Sn, (long long)Sn * Dn);

    // adjacency softmax + node mask last (its region doubled as densebf scratch)
    adjsm_mask_kernel<<<Bn * Sn, 256, 0, stream>>>(adj, colsum, out + OFF_ADJ, out + OFF_MASK);
}

// Round 3
// 186.282 us; speedup vs baseline: 3.7033x; 1.9765x over previous
//
#include <hip/hip_runtime.h>
#include <hip/hip_bf16.h>
#include <math.h>

// Problem sizes (fixed by reference)
static constexpr int Bn = 16, Sn = 512, Wn = 8, Dn = 768;
static constexpr int Mn_ = 2, WMn = 64;
static constexpr int Un = 32, WUn = 16;

#define INF_VAL 1e12f
#define INV_SQRT_D 0.03608439182435161f

// Output float offsets
static constexpr size_t OFF_GCN   = 0;                    // [16,512,768]
static constexpr size_t OFF_MASK  = 6291456;              // [16,512,1]
static constexpr size_t OFF_DENSE = 6299648;              // [16,512,512]
static constexpr size_t OFF_ADJ   = 10493952;             // [16,512,512]
static constexpr size_t OFF_MAIN  = 14688256;             // [16,2,768]
static constexpr size_t OFF_USER  = 14712832;             // [16,768]

// Workspace byte offsets
static constexpr size_t WSB_GBF    = 0;          // g bf16 [8192][768]      12582912 B
static constexpr size_t WSB_GT     = 12582912;   // gT bf16 [16][768][512]  12582912 B
static constexpr size_t WSB_KBAR   = 25165824;   // double[768]
static constexpr size_t WSB_QBAR   = 25171968;   // double[768]
static constexpr size_t WSB_U      = 25178112;   // double[768]
static constexpr size_t WSB_V      = 25184256;   // double[768]
static constexpr size_t WSB_CONSTS = 25190400;   // double[4]: c0,c1,c2
static constexpr size_t WSB_QS     = 25190464;   // float[8192]
static constexpr size_t WSB_KQ     = 25223232;   // float[8192]
static constexpr size_t WSB_COLSUM = 25256000;   // float[8192]
static constexpr size_t WSB_FLAGS  = 25288768;   // int[8192]

// Scratch byte offsets inside the ADJ output region (16777216 B), all dead
// before adjsm_mask_kernel runs last:
static constexpr size_t ADJB_DENSEBF = 0;          // ushort[8192*512] = 8388608
static constexpr size_t ADJB_PARTU   = 8388608;    // f32 [512][768]  = 1572864
static constexpr size_t ADJB_PARTM   = 9961472;    // f32 [128][768]  =  393216
static constexpr size_t ADJB_UVU     = 10354688;   // f64 [8][768]    =   49152
static constexpr size_t ADJB_UVV     = 10403840;   // f64 [8][768]    =   49152
static constexpr size_t ADJB_CPART   = 10452992;   // f32 [32][16][512] = 1048576

typedef __attribute__((ext_vector_type(8))) short short8;
typedef __attribute__((ext_vector_type(4))) float f32x4;

static __device__ __forceinline__ ushort f2bf(float f) {
    union { float f; unsigned u; } v; v.f = f;
    unsigned u = v.u;
    unsigned r = (u + 0x7FFFu + ((u >> 16) & 1u)) >> 16;
    return (ushort)r;
}

static __device__ __forceinline__ void gload16(const void* g, void* lds) {
    __builtin_amdgcn_global_load_lds(
        (const __attribute__((address_space(1))) void*)g,
        (__attribute__((address_space(3))) void*)lds, 16, 0, 0);
}

static __device__ __forceinline__ void fmax4(float4& a, const float4& x) {
    a.x = fmaxf(a.x, x.x); a.y = fmaxf(a.y, x.y);
    a.z = fmaxf(a.z, x.z); a.w = fmaxf(a.w, x.w);
}

// ---------------------------------------------------------------------------
// Weight folds (f64 for masked-score argmax fidelity)
__global__ __launch_bounds__(64)
void bar_kernel(const float* __restrict__ K_w, const float* __restrict__ K_b,
                const float* __restrict__ Q_w, const float* __restrict__ Q_b,
                double* __restrict__ kbar, double* __restrict__ qbar) {
    int e = blockIdx.x;
    int l = threadIdx.x;
    double sk = 0.0, sq = 0.0;
    for (int d = l; d < Dn; d += 64) {
        sk += (double)K_w[(size_t)e * Dn + d];
        sq += (double)Q_w[(size_t)e * Dn + d];
    }
    #pragma unroll
    for (int off = 32; off > 0; off >>= 1) {
        sk += __shfl_down(sk, off, 64);
        sq += __shfl_down(sq, off, 64);
    }
    if (l == 0) {
        kbar[e] = -1e12 * sk + (double)K_b[e];
        qbar[e] = -1e12 * sq + (double)Q_b[e];
    }
}

// u_j = sum_e K_w[e,j]*qbar_e ; v_j = sum_e Q_w[e,j]*kbar_e — parallel partials
__global__ __launch_bounds__(64)
void uv_part(const float* __restrict__ K_w, const float* __restrict__ Q_w,
             const double* __restrict__ kbar, const double* __restrict__ qbar,
             double* __restrict__ uvu, double* __restrict__ uvv) {
    int j = blockIdx.x * 64 + threadIdx.x;
    int e0 = blockIdx.y * 96;
    double su = 0.0, sv = 0.0;
    for (int e = e0; e < e0 + 96; ++e) {
        su += (double)K_w[(size_t)e * Dn + j] * qbar[e];
        sv += (double)Q_w[(size_t)e * Dn + j] * kbar[e];
    }
    uvu[(size_t)blockIdx.y * Dn + j] = su;
    uvv[(size_t)blockIdx.y * Dn + j] = sv;
}

__global__ __launch_bounds__(64)
void uv_reduce(const double* __restrict__ uvu, const double* __restrict__ uvv,
               double* __restrict__ u, double* __restrict__ v) {
    int j = blockIdx.x * 64 + threadIdx.x;
    double su = 0.0, sv = 0.0;
    #pragma unroll
    for (int c = 0; c < 8; ++c) {
        su += uvu[(size_t)c * Dn + j];
        sv += uvv[(size_t)c * Dn + j];
    }
    u[j] = su; v[j] = sv;
}

// c0 = kbar.Q_b ; c1 = kbar.qbar ; c2 = qbar.K_b
__global__ __launch_bounds__(64)
void consts_kernel(const double* __restrict__ kbar, const double* __restrict__ qbar,
                   const float* __restrict__ K_b, const float* __restrict__ Q_b,
                   double* __restrict__ consts) {
    int l = threadIdx.x;
    double c0 = 0.0, c1 = 0.0, c2 = 0.0;
    for (int e = l; e < Dn; e += 64) {
        c0 += kbar[e] * (double)Q_b[e];
        c1 += kbar[e] * qbar[e];
        c2 += qbar[e] * (double)K_b[e];
    }
    #pragma unroll
    for (int off = 32; off > 0; off >>= 1) {
        c0 += __shfl_down(c0, off, 64);
        c1 += __shfl_down(c1, off, 64);
        c2 += __shfl_down(c2, off, 64);
    }
    if (l == 0) { consts[0] = c0; consts[1] = c1; consts[2] = c2; }
}

// f32 -> bf16 bulk convert
__global__ __launch_bounds__(256)
void cvt_bf16(const float* __restrict__ in, ushort* __restrict__ out, int n) {
    int i = blockIdx.x * 256 + threadIdx.x;
    if (i * 4 < n) {
        float4 v = ((const float4*)in)[i];
        ushort4 o;
        o.x = f2bf(v.x); o.y = f2bf(v.y); o.z = f2bf(v.z); o.w = f2bf(v.w);
        ((ushort4*)out)[i] = o;
    }
}

// ---------------------------------------------------------------------------
// g pool: bf16 g + exact f32-row dots qs/kq (f64 accum) + row-masked flag.
__global__ __launch_bounds__(192)
void pool_g_kernel(const int* __restrict__ words, const int* __restrict__ masks,
                   const float* __restrict__ emb,
                   const double* __restrict__ u, const double* __restrict__ v,
                   const double* __restrict__ consts,
                   ushort* __restrict__ gbf, float* __restrict__ qs,
                   float* __restrict__ kq, int* __restrict__ flags) {
    int bs = blockIdx.x;
    int t = threadIdx.x;
    const int* wrow = words + (size_t)bs * Wn;
    const int* mrow = masks + (size_t)bs * Wn;
    float4 acc = make_float4(-INF_VAL, -INF_VAL, -INF_VAL, -INF_VAL);
    int nm = 0;
    #pragma unroll
    for (int w = 0; w < Wn; ++w) {
        int mk = mrow[w];
        nm += (mk != 0);
        if (mk != 0) continue;
        float4 x = ((const float4*)(emb + (size_t)wrow[w] * Dn))[t];
        fmax4(acc, x);
    }
    ushort4 o;
    o.x = f2bf(acc.x); o.y = f2bf(acc.y); o.z = f2bf(acc.z); o.w = f2bf(acc.w);
    ((ushort4*)(gbf + (size_t)bs * Dn))[t] = o;
    int j = t * 4;
    double dv = v[j] * (double)acc.x + v[j+1] * (double)acc.y
              + v[j+2] * (double)acc.z + v[j+3] * (double)acc.w;
    double du = u[j] * (double)acc.x + u[j+1] * (double)acc.y
              + u[j+2] * (double)acc.z + u[j+3] * (double)acc.w;
    #pragma unroll
    for (int off = 32; off > 0; off >>= 1) {
        dv += __shfl_down(dv, off, 64);
        du += __shfl_down(du, off, 64);
    }
    __shared__ double rr[6];
    if ((t & 63) == 0) { rr[t >> 6] = dv; rr[3 + (t >> 6)] = du; }
    __syncthreads();
    if (t == 0) {
        qs[bs] = (float)(rr[0] + rr[1] + rr[2] + consts[0]);
        kq[bs] = (float)(rr[3] + rr[4] + rr[5] + consts[2]);
        flags[bs] = (nm == Wn) ? 1 : 0;
    }
}

// main pool, two stage: stage1 = 16-piece partial max per block
__global__ __launch_bounds__(192)
void pool_main_s1(const int* __restrict__ main_idx, const int* __restrict__ mmask,
                  const float* __restrict__ emb, float* __restrict__ partM) {
    int blk = blockIdx.x;          // [B*M*4]
    int bm = blk >> 2, ch = blk & 3;
    int t = threadIdx.x;
    const int* irow = main_idx + (size_t)bm * WMn + ch * 16;
    const int* mrow = mmask + (size_t)bm * WMn + ch * 16;
    float4 acc = make_float4(-INF_VAL, -INF_VAL, -INF_VAL, -INF_VAL);
    #pragma unroll
    for (int w = 0; w < 16; ++w) {
        if (mrow[w] != 0) continue;
        float4 x = ((const float4*)(emb + (size_t)irow[w] * Dn))[t];
        fmax4(acc, x);
    }
    ((float4*)(partM + (size_t)blk * Dn))[t] = acc;
}

__global__ __launch_bounds__(192)
void pool_main_s2(const float* __restrict__ partM, float* __restrict__ out) {
    int bm = blockIdx.x;
    int t = threadIdx.x;
    float4 acc = make_float4(-INF_VAL, -INF_VAL, -INF_VAL, -INF_VAL);
    #pragma unroll
    for (int c = 0; c < 4; ++c) {
        float4 x = ((const float4*)(partM + (size_t)(bm * 4 + c) * Dn))[t];
        fmax4(acc, x);
    }
    if (acc.x == -INF_VAL) acc.x = 0.f;
    if (acc.y == -INF_VAL) acc.y = 0.f;
    if (acc.z == -INF_VAL) acc.z = 0.f;
    if (acc.w == -INF_VAL) acc.w = 0.f;
    ((float4*)(out + (size_t)bm * Dn))[t] = acc;
}

// user pool, two stage: stage1 = one user per block
__global__ __launch_bounds__(192)
void pool_user_s1(const int* __restrict__ user_idx, const int* __restrict__ umask,
                  const float* __restrict__ emb, float* __restrict__ partU) {
    int bu = blockIdx.x;           // [B*U]
    int t = threadIdx.x;
    const int* irow = user_idx + (size_t)bu * WUn;
    const int* mrow = umask + (size_t)bu * WUn;
    float4 acc = make_float4(-INF_VAL, -INF_VAL, -INF_VAL, -INF_VAL);
    #pragma unroll
    for (int w = 0; w < WUn; ++w) {
        if (mrow[w] != 0) continue;
        float4 x = ((const float4*)(emb + (size_t)irow[w] * Dn))[t];
        fmax4(acc, x);
    }
    ((float4*)(partU + (size_t)bu * Dn))[t] = acc;
}

__global__ __launch_bounds__(192)
void pool_user_s2(const float* __restrict__ partU, float* __restrict__ out) {
    int b = blockIdx.x;
    int t = threadIdx.x;
    float4 acc = make_float4(-INF_VAL, -INF_VAL, -INF_VAL, -INF_VAL);
    for (int u2 = 0; u2 < Un; ++u2) {
        float4 x = ((const float4*)(partU + (size_t)(b * Un + u2) * Dn))[t];
        fmax4(acc, x);
    }
    if (acc.x == -INF_VAL) acc.x = 0.f;
    if (acc.y == -INF_VAL) acc.y = 0.f;
    if (acc.z == -INF_VAL) acc.z = 0.f;
    if (acc.w == -INF_VAL) acc.w = 0.f;
    ((float4*)(out + (size_t)b * Dn))[t] = acc;
}

// colsum partials: block (b, chunk) sums 16 s-rows
__global__ __launch_bounds__(512)
void colsum_part(const float* __restrict__ adj, float* __restrict__ cpart) {
    int b = blockIdx.x, ch = blockIdx.y;
    int t = threadIdx.x;
    const float* base = adj + (size_t)b * Sn * Sn + (size_t)ch * 16 * Sn;
    float acc = 0.f;
    #pragma unroll
    for (int s = 0; s < 16; ++s) acc += base[(size_t)s * Sn + t];
    cpart[((size_t)ch * Bn + b) * Sn + t] = acc;
}

__global__ __launch_bounds__(512)
void colsum_reduce(const float* __restrict__ cpart, float* __restrict__ colsum) {
    int b = blockIdx.x;
    int t = threadIdx.x;
    float acc = 0.f;
    #pragma unroll
    for (int c = 0; c < 32; ++c) acc += cpart[((size_t)c * Bn + b) * Sn + t];
    colsum[(size_t)b * Sn + t] = acc;
}

// adj softmax (0/1 entries) + node mask
__global__ __launch_bounds__(256)
void adjsm_mask_kernel(const float* __restrict__ adj, const float* __restrict__ colsum,
                       float* __restrict__ adjsm, float* __restrict__ maskout) {
    int bs = blockIdx.x;
    int t = threadIdx.x;
    const float* row = adj + (size_t)bs * Sn;
    float a0 = row[t], a1 = row[t + 256];
    float local = a0 + a1;
    #pragma unroll
    for (int off = 32; off > 0; off >>= 1) local += __shfl_down(local, off, 64);
    __shared__ float red[4];
    __shared__ float bc;
    if ((t & 63) == 0) red[t >> 6] = local;
    __syncthreads();
    if (t == 0) {
        float n1 = red[0] + red[1] + red[2] + red[3];
        bc = n1;
        float cs = colsum[bs];
        maskout[bs] = ((n1 + cs) == 0.0f) ? 1.0f : 0.0f;
    }
    __syncthreads();
    float n1 = bc;
    float mx = (n1 > 0.f) ? 1.f : 0.f;
    float e1 = expf(1.f - mx);
    float e0 = expf(0.f - mx);
    float denom = n1 * e1 + (512.f - n1) * e0;
    float inv = 1.f / denom;
    float* outr = adjsm + (size_t)bs * Sn;
    outr[t]       = (a0 == 1.f ? e1 : e0) * inv;
    outr[t + 256] = (a1 == 1.f ? e1 : e0) * inv;
}

// transpose bf16 g -> gT[b][d][s]
__global__ __launch_bounds__(256)
void transpose_g(const ushort* __restrict__ gbf, ushort* __restrict__ gT) {
    __shared__ ushort tile[32][33];
    int b = blockIdx.z;
    int d0 = blockIdx.x * 32, s0 = blockIdx.y * 32;
    int tx = threadIdx.x & 31, ty = threadIdx.x >> 5;
    #pragma unroll
    for (int i = 0; i < 4; ++i)
        tile[ty + i * 8][tx] = gbf[((size_t)(b * Sn + s0 + ty + i * 8)) * Dn + d0 + tx];
    __syncthreads();
    #pragma unroll
    for (int i = 0; i < 4; ++i)
        gT[((size_t)(b * Dn + d0 + ty + i * 8)) * Sn + s0 + tx] = tile[tx][ty + i * 8];
}

// ---------------------------------------------------------------------------
// bf16 MFMA GEMM: C[m][n] = sum_k A[m][k]*B[n][k] (+bias[n])
// 128x128 tile, BK=64, 256 threads = 4 waves (2x2), 16x16x32 MFMA.
template<int OUT_BF16, int HASBIAS>
__global__ __launch_bounds__(256)
void gemm_mfma(const ushort* __restrict__ A, const ushort* __restrict__ B,
               const float* __restrict__ bias, void* __restrict__ Cout,
               int Km, int lda, int ldb, int ldc,
               long long sA, long long sB, long long sC) {
    __shared__ ushort As[128 * 64];
    __shared__ ushort Bs[128 * 64];
    const ushort* Ab = A + (size_t)blockIdx.z * sA;
    const ushort* Bb = B + (size_t)blockIdx.z * sB;
    int i0 = blockIdx.y * 128, j0 = blockIdx.x * 128;
    int tid = threadIdx.x;
    int lane = tid & 63, wv = tid >> 6;
    int wr = wv >> 1, wc = wv & 1;
    int ln15 = lane & 15, lkg = lane >> 4;
    int sub = lane >> 3;
    int c8  = lane & 7;

    f32x4 acc[4][4] = {};

    for (int k0 = 0; k0 < Km; k0 += 64) {
        #pragma unroll
        for (int it = 0; it < 4; ++it) {
            int r = it * 32 + wv * 8 + sub;
            int cc = c8 ^ (r & 7);
            ushort* dstA = As + (it * 4096 + wv * 1024) / 2;
            ushort* dstB = Bs + (it * 4096 + wv * 1024) / 2;
            gload16(Ab + (size_t)(i0 + r) * lda + k0 + cc * 8, dstA);
            gload16(Bb + (size_t)(j0 + r) * ldb + k0 + cc * 8, dstB);
        }
        __syncthreads();
        #pragma unroll
        for (int kh = 0; kh < 2; ++kh) {
            short8 af[4], bfr[4];
            int kc = kh * 4 + lkg;
            #pragma unroll
            for (int f = 0; f < 4; ++f) {
                int ra = wr * 64 + f * 16 + ln15;
                af[f] = *(const short8*)((const char*)As + ra * 128 + ((kc ^ (ra & 7)) << 4));
                int rb = wc * 64 + f * 16 + ln15;
                bfr[f] = *(const short8*)((const char*)Bs + rb * 128 + ((kc ^ (rb & 7)) << 4));
            }
            #pragma unroll
            for (int fa = 0; fa < 4; ++fa)
                #pragma unroll
                for (int fb = 0; fb < 4; ++fb)
                    acc[fa][fb] = __builtin_amdgcn_mfma_f32_16x16x32_bf16(
                        af[fa], bfr[fb], acc[fa][fb], 0, 0, 0);
        }
        __syncthreads();
    }

    #pragma unroll
    for (int fa = 0; fa < 4; ++fa) {
        #pragma unroll
        for (int fb = 0; fb < 4; ++fb) {
            int n = j0 + wc * 64 + fb * 16 + ln15;
            float bv = HASBIAS ? bias[n] : 0.0f;
            #pragma unroll
            for (int rr = 0; rr < 4; ++rr) {
                int m = i0 + wr * 64 + fa * 16 + lkg * 4 + rr;
                float val = acc[fa][fb][rr] + bv;
                if (OUT_BF16) {
                    ((ushort*)Cout)[(size_t)blockIdx.z * sC + (size_t)m * ldc + n] = f2bf(val);
                } else {
                    ((float*)Cout)[(size_t)blockIdx.z * sC + (size_t)m * ldc + n] = val;
                }
            }
        }
    }
}

// ---------------------------------------------------------------------------
// scores fixup + row softmax. Overrides masked rows/cols with exact rank-1 values.
__global__ __launch_bounds__(256)
void softmax_fix(float* __restrict__ dense, const int* __restrict__ flags,
                 const float* __restrict__ qs, const float* __restrict__ kq,
                 const double* __restrict__ consts, ushort* __restrict__ densebf) {
    int bs = blockIdx.x;
    int b = bs >> 9;
    int t = threadIdx.x;
    float* row = dense + (size_t)bs * 512;
    int f0 = flags[(b << 9) + t];
    int f1 = flags[(b << 9) + t + 256];
    bool sm = flags[bs] != 0;
    float x0, x1;
    if (sm) {
        float c1i = (float)consts[1] * INV_SQRT_D;
        x0 = f0 ? c1i : qs[(b << 9) + t] * INV_SQRT_D;
        x1 = f1 ? c1i : qs[(b << 9) + t + 256] * INV_SQRT_D;
    } else {
        float kqi = kq[bs] * INV_SQRT_D;
        x0 = f0 ? kqi : row[t] * INV_SQRT_D;
        x1 = f1 ? kqi : row[t + 256] * INV_SQRT_D;
    }
    float m = fmaxf(x0, x1);
    #pragma unroll
    for (int off = 32; off > 0; off >>= 1) m = fmaxf(m, __shfl_down(m, off, 64));
    __shared__ float red[4];
    __shared__ float bmax, bsum;
    if ((t & 63) == 0) red[t >> 6] = m;
    __syncthreads();
    if (t == 0) bmax = fmaxf(fmaxf(red[0], red[1]), fmaxf(red[2], red[3]));
    __syncthreads();
    float mx = bmax;
    float e0 = expf(x0 - mx), e1 = expf(x1 - mx);
    float s = e0 + e1;
    #pragma unroll
    for (int off = 32; off > 0; off >>= 1) s += __shfl_down(s, off, 64);
    if ((t & 63) == 0) red[t >> 6] = s;
    __syncthreads();
    if (t == 0) bsum = red[0] + red[1] + red[2] + red[3];
    __syncthreads();
    float inv = 1.f / bsum;
    float p0 = e0 * inv, p1 = e1 * inv;
    row[t] = p0; row[t + 256] = p1;
    ushort* bro = densebf + (size_t)bs * 512;
    bro[t] = f2bf(p0); bro[t + 256] = f2bf(p1);
}

// ---------------------------------------------------------------------------
extern "C" void kernel_launch(void* const* d_in, const int* in_sizes, int n_in,
                              void* d_out, int out_size, void* d_ws, size_t ws_size,
                              hipStream_t stream) {
    const int*   words     = (const int*)d_in[0];
    const int*   masks     = (const int*)d_in[1];
    const int*   main_idx  = (const int*)d_in[2];
    const int*   main_mask = (const int*)d_in[3];
    const int*   user_idx  = (const int*)d_in[4];
    const int*   user_mask = (const int*)d_in[5];
    const float* adj       = (const float*)d_in[6];
    const float* emb       = (const float*)d_in[7];
    const float* K_w       = (const float*)d_in[8];
    const float* K_b       = (const float*)d_in[9];
    const float* Q_w       = (const float*)d_in[10];
    const float* Q_b       = (const float*)d_in[11];

    float* out = (float*)d_out;
    char*  ws8 = (char*)d_ws;

    ushort* gbf    = (ushort*)(ws8 + WSB_GBF);
    ushort* gT     = (ushort*)(ws8 + WSB_GT);
    double* kbar   = (double*)(ws8 + WSB_KBAR);
    double* qbar   = (double*)(ws8 + WSB_QBAR);
    double* u      = (double*)(ws8 + WSB_U);
    double* v      = (double*)(ws8 + WSB_V);
    double* consts = (double*)(ws8 + WSB_CONSTS);
    float*  qs     = (float*)(ws8 + WSB_QS);
    float*  kq     = (float*)(ws8 + WSB_KQ);
    float*  colsum = (float*)(ws8 + WSB_COLSUM);
    int*    flags  = (int*)(ws8 + WSB_FLAGS);

    // scratch parked in output regions (all fully rewritten later each call)
    char*   adjsc   = (char*)(out + OFF_ADJ);
    ushort* densebf = (ushort*)(adjsc + ADJB_DENSEBF);
    float*  partU   = (float*)(adjsc + ADJB_PARTU);
    float*  partM   = (float*)(adjsc + ADJB_PARTM);
    double* uvu     = (double*)(adjsc + ADJB_UVU);
    double* uvv     = (double*)(adjsc + ADJB_UVV);
    float*  cpart   = (float*)(adjsc + ADJB_CPART);

    ushort* Kwb     = (ushort*)(out + OFF_DENSE);              // dead before scores GEMM
    ushort* Qwb     = Kwb + (size_t)Dn * Dn;
    ushort* keybf   = (ushort*)(out + OFF_GCN);                // dead before gcn GEMM
    ushort* querybf = keybf + (size_t)Bn * Sn * Dn;
    float*  dense   = out + OFF_DENSE;

    // weight folds (batch-independent)
    bar_kernel<<<Dn, 64, 0, stream>>>(K_w, K_b, Q_w, Q_b, kbar, qbar);
    uv_part<<<dim3(Dn / 64, 8), 64, 0, stream>>>(K_w, Q_w, kbar, qbar, uvu, uvv);
    uv_reduce<<<Dn / 64, 64, 0, stream>>>(uvu, uvv, u, v);
    consts_kernel<<<1, 64, 0, stream>>>(kbar, qbar, K_b, Q_b, consts);
    cvt_bf16<<<(Dn * Dn / 4 + 255) / 256, 256, 0, stream>>>(K_w, Kwb, Dn * Dn);
    cvt_bf16<<<(Dn * Dn / 4 + 255) / 256, 256, 0, stream>>>(Q_w, Qwb, Dn * Dn);

    // pools (parallel stages)
    pool_g_kernel<<<Bn * Sn, 192, 0, stream>>>(words, masks, emb, u, v, consts,
                                               gbf, qs, kq, flags);
    pool_main_s1<<<Bn * Mn_ * 4, 192, 0, stream>>>(main_idx, main_mask, emb, partM);
    pool_main_s2<<<Bn * Mn_, 192, 0, stream>>>(partM, out + OFF_MAIN);
    pool_user_s1<<<Bn * Un, 192, 0, stream>>>(user_idx, user_mask, emb, partU);
    pool_user_s2<<<Bn, 192, 0, stream>>>(partU, out + OFF_USER);

    // adjacency column sums (parallel partials)
    colsum_part<<<dim3(Bn, 32), 512, 0, stream>>>(adj, cpart);
    colsum_reduce<<<Bn, 512, 0, stream>>>(cpart, colsum);

    transpose_g<<<dim3(Dn / 32, Sn / 32, Bn), 256, 0, stream>>>(gbf, gT);

    // key = g @ K_w^T + K_b (bf16 out) ; query likewise
    gemm_mfma<1, 1><<<dim3(Dn / 128, (Bn * Sn) / 128, 1), 256, 0, stream>>>(
        gbf, Kwb, K_b, keybf, Dn, Dn, Dn, Dn, 0, 0, 0);
    gemm_mfma<1, 1><<<dim3(Dn / 128, (Bn * Sn) / 128, 1), 256, 0, stream>>>(
        gbf, Qwb, Q_b, querybf, Dn, Dn, Dn, Dn, 0, 0, 0);

    // raw scores[b] = key[b] @ query[b]^T (f32 out, scale applied in softmax)
    gemm_mfma<0, 0><<<dim3(Sn / 128, Sn / 128, Bn), 256, 0, stream>>>(
        keybf, querybf, nullptr, dense, Dn, Dn, Dn, Sn,
        (long long)Sn * Dn, (long long)Sn * Dn, (long long)Sn * Sn);

    // fixup masked rows/cols + softmax; writes f32 dense + bf16 copy
    softmax_fix<<<Bn * Sn, 256, 0, stream>>>(dense, flags, qs, kq, consts, densebf);

    // gcn[b] = P[b] @ g[b] = densebf @ gT^T (f32 out)
    gemm_mfma<0, 0><<<dim3(Dn / 128, Sn / 128, Bn), 256, 0, stream>>>(
        densebf, gT, nullptr, out + OFF_GCN, Sn, Sn, Sn, Dn,
        (long long)Sn * Sn, (long long)Dn * Sn, (long long)Sn * Dn);

    // adjacency softmax + node mask last (its region doubled as scratch)
    adjsm_mask_kernel<<<Bn * Sn, 256, 0, stream>>>(adj, colsum, out + OFF_ADJ, out + OFF_MASK);
}

// Round 4
// 178.168 us; speedup vs baseline: 3.8720x; 1.0455x over previous
//
#include <hip/hip_runtime.h>
#include <hip/hip_bf16.h>
#include <math.h>

// Problem sizes (fixed by reference)
static constexpr int Bn = 16, Sn = 512, Wn = 8, Dn = 768;
static constexpr int Mn_ = 2, WMn = 64;
static constexpr int Un = 32, WUn = 16;

#define INF_VAL 1e12f
#define INV_SQRT_D 0.03608439182435161f

// Output float offsets
static constexpr size_t OFF_GCN   = 0;                    // [16,512,768]
static constexpr size_t OFF_MASK  = 6291456;              // [16,512,1]
static constexpr size_t OFF_DENSE = 6299648;              // [16,512,512]
static constexpr size_t OFF_ADJ   = 10493952;             // [16,512,512]
static constexpr size_t OFF_MAIN  = 14688256;             // [16,2,768]
static constexpr size_t OFF_USER  = 14712832;             // [16,768]

// Workspace byte offsets
static constexpr size_t WSB_GBF    = 0;          // g bf16 [8192][768]      12582912 B
static constexpr size_t WSB_GT     = 12582912;   // gT bf16 [16][768][512]  12582912 B
static constexpr size_t WSB_KBAR   = 25165824;   // double[768]
static constexpr size_t WSB_QBAR   = 25171968;   // double[768]
static constexpr size_t WSB_U      = 25178112;   // double[768]
static constexpr size_t WSB_V      = 25184256;   // double[768]
static constexpr size_t WSB_CONSTS = 25190400;   // double[4]: c0,c1,c2
static constexpr size_t WSB_QS     = 25190464;   // float[8192]
static constexpr size_t WSB_KQ     = 25223232;   // float[8192]
static constexpr size_t WSB_COLSUM = 25256000;   // float[8192]
static constexpr size_t WSB_FLAGS  = 25288768;   // int[8192]; ALIASED as rowsum
                                                 // (flags dead after softmax_fix,
                                                 //  rowsum written after it)

// Scratch inside the ADJ output region (16777216 B), all dead before the
// final adjsm_colsum overwrite:
static constexpr size_t ADJB_DENSEBF = 0;          // ushort[8192*512] = 8388608
static constexpr size_t ADJB_PARTU   = 8388608;    // f32 [512][768]  = 1572864
static constexpr size_t ADJB_PARTM   = 9961472;    // f32 [128][768]  =  393216
static constexpr size_t ADJB_UVU     = 10354688;   // f64 [8][768]    =   49152
static constexpr size_t ADJB_UVV     = 10403840;   // f64 [8][768]    =   49152
static constexpr size_t ADJB_BCAT    = 10452992;   // f32 [1536]      =    6144

typedef __attribute__((ext_vector_type(8))) short short8;
typedef __attribute__((ext_vector_type(4))) float f32x4;

static __device__ __forceinline__ ushort f2bf(float f) {
    union { float f; unsigned u; } v; v.f = f;
    unsigned u = v.u;
    unsigned r = (u + 0x7FFFu + ((u >> 16) & 1u)) >> 16;
    return (ushort)r;
}

static __device__ __forceinline__ void gload16(const void* g, void* lds) {
    __builtin_amdgcn_global_load_lds(
        (const __attribute__((address_space(1))) void*)g,
        (__attribute__((address_space(3))) void*)lds, 16, 0, 0);
}

static __device__ __forceinline__ void fmax4(float4& a, const float4& x) {
    a.x = fmaxf(a.x, x.x); a.y = fmaxf(a.y, x.y);
    a.z = fmaxf(a.z, x.z); a.w = fmaxf(a.w, x.w);
}

// ---------------------------------------------------------------------------
// Weight folds (f64 for masked-score argmax fidelity)
__global__ __launch_bounds__(64)
void bar_kernel(const float* __restrict__ K_w, const float* __restrict__ K_b,
                const float* __restrict__ Q_w, const float* __restrict__ Q_b,
                double* __restrict__ kbar, double* __restrict__ qbar) {
    int e = blockIdx.x;
    int l = threadIdx.x;
    double sk = 0.0, sq = 0.0;
    for (int d = l; d < Dn; d += 64) {
        sk += (double)K_w[(size_t)e * Dn + d];
        sq += (double)Q_w[(size_t)e * Dn + d];
    }
    #pragma unroll
    for (int off = 32; off > 0; off >>= 1) {
        sk += __shfl_down(sk, off, 64);
        sq += __shfl_down(sq, off, 64);
    }
    if (l == 0) {
        kbar[e] = -1e12 * sk + (double)K_b[e];
        qbar[e] = -1e12 * sq + (double)Q_b[e];
    }
}

// u_j = sum_e K_w[e,j]*qbar_e ; v_j = sum_e Q_w[e,j]*kbar_e — parallel partials
__global__ __launch_bounds__(64)
void uv_part(const float* __restrict__ K_w, const float* __restrict__ Q_w,
             const double* __restrict__ kbar, const double* __restrict__ qbar,
             double* __restrict__ uvu, double* __restrict__ uvv) {
    int j = blockIdx.x * 64 + threadIdx.x;
    int e0 = blockIdx.y * 96;
    double su = 0.0, sv = 0.0;
    for (int e = e0; e < e0 + 96; ++e) {
        su += (double)K_w[(size_t)e * Dn + j] * qbar[e];
        sv += (double)Q_w[(size_t)e * Dn + j] * kbar[e];
    }
    uvu[(size_t)blockIdx.y * Dn + j] = su;
    uvv[(size_t)blockIdx.y * Dn + j] = sv;
}

// blocks 0..11: uv reduce; block 12: consts c0,c1,c2
__global__ __launch_bounds__(64)
void uvred_consts(const double* __restrict__ uvu, const double* __restrict__ uvv,
                  const double* __restrict__ kbar, const double* __restrict__ qbar,
                  const float* __restrict__ K_b, const float* __restrict__ Q_b,
                  double* __restrict__ u, double* __restrict__ v,
                  double* __restrict__ consts) {
    int blk = blockIdx.x;
    int l = threadIdx.x;
    if (blk < 12) {
        int j = blk * 64 + l;
        double su = 0.0, sv = 0.0;
        #pragma unroll
        for (int c = 0; c < 8; ++c) {
            su += uvu[(size_t)c * Dn + j];
            sv += uvv[(size_t)c * Dn + j];
        }
        u[j] = su; v[j] = sv;
    } else {
        double c0 = 0.0, c1 = 0.0, c2 = 0.0;
        for (int e = l; e < Dn; e += 64) {
            c0 += kbar[e] * (double)Q_b[e];
            c1 += kbar[e] * qbar[e];
            c2 += qbar[e] * (double)K_b[e];
        }
        #pragma unroll
        for (int off = 32; off > 0; off >>= 1) {
            c0 += __shfl_down(c0, off, 64);
            c1 += __shfl_down(c1, off, 64);
            c2 += __shfl_down(c2, off, 64);
        }
        if (l == 0) { consts[0] = c0; consts[1] = c1; consts[2] = c2; }
    }
}

// f32 -> bf16 for K_w (y=0) and Q_w (y=1)
__global__ __launch_bounds__(256)
void cvt2_bf16(const float* __restrict__ K_w, const float* __restrict__ Q_w,
               ushort* __restrict__ Kwb, ushort* __restrict__ Qwb) {
    int i = blockIdx.x * 256 + threadIdx.x;
    const float* in = blockIdx.y ? Q_w : K_w;
    ushort* outp = blockIdx.y ? Qwb : Kwb;
    float4 x = ((const float4*)in)[i];
    ushort4 o;
    o.x = f2bf(x.x); o.y = f2bf(x.y); o.z = f2bf(x.z); o.w = f2bf(x.w);
    ((ushort4*)outp)[i] = o;
}

// bias concat [K_b||Q_b] + zero colsum
__global__ __launch_bounds__(256)
void misc_init(const float* __restrict__ K_b, const float* __restrict__ Q_b,
               float* __restrict__ bcat, float* __restrict__ colsum) {
    int i = blockIdx.x * 256 + threadIdx.x;
    if (i < 1536) bcat[i] = (i < 768) ? K_b[i] : Q_b[i - 768];
    colsum[i] = 0.f;   // grid covers 8192
}

// ---------------------------------------------------------------------------
// g pool: bf16 g + exact f32-row dots qs/kq (f64 accum) + row-masked flag.
__global__ __launch_bounds__(192)
void pool_g_kernel(const int* __restrict__ words, const int* __restrict__ masks,
                   const float* __restrict__ emb,
                   const double* __restrict__ u, const double* __restrict__ v,
                   const double* __restrict__ consts,
                   ushort* __restrict__ gbf, float* __restrict__ qs,
                   float* __restrict__ kq, int* __restrict__ flags) {
    int bs = blockIdx.x;
    int t = threadIdx.x;
    const int* wrow = words + (size_t)bs * Wn;
    const int* mrow = masks + (size_t)bs * Wn;
    float4 acc = make_float4(-INF_VAL, -INF_VAL, -INF_VAL, -INF_VAL);
    int nm = 0;
    #pragma unroll
    for (int w = 0; w < Wn; ++w) {
        int mk = mrow[w];
        nm += (mk != 0);
        if (mk != 0) continue;
        float4 x = ((const float4*)(emb + (size_t)wrow[w] * Dn))[t];
        fmax4(acc, x);
    }
    ushort4 o;
    o.x = f2bf(acc.x); o.y = f2bf(acc.y); o.z = f2bf(acc.z); o.w = f2bf(acc.w);
    ((ushort4*)(gbf + (size_t)bs * Dn))[t] = o;
    int j = t * 4;
    double dv = v[j] * (double)acc.x + v[j+1] * (double)acc.y
              + v[j+2] * (double)acc.z + v[j+3] * (double)acc.w;
    double du = u[j] * (double)acc.x + u[j+1] * (double)acc.y
              + u[j+2] * (double)acc.z + u[j+3] * (double)acc.w;
    #pragma unroll
    for (int off = 32; off > 0; off >>= 1) {
        dv += __shfl_down(dv, off, 64);
        du += __shfl_down(du, off, 64);
    }
    __shared__ double rr[6];
    if ((t & 63) == 0) { rr[t >> 6] = dv; rr[3 + (t >> 6)] = du; }
    __syncthreads();
    if (t == 0) {
        qs[bs] = (float)(rr[0] + rr[1] + rr[2] + consts[0]);
        kq[bs] = (float)(rr[3] + rr[4] + rr[5] + consts[2]);
        flags[bs] = (nm == Wn) ? 1 : 0;
    }
}

// main pool stage1 = 16-piece partial max per block
__global__ __launch_bounds__(192)
void pool_main_s1(const int* __restrict__ main_idx, const int* __restrict__ mmask,
                  const float* __restrict__ emb, float* __restrict__ partM) {
    int blk = blockIdx.x;          // [B*M*4]
    int bm = blk >> 2, ch = blk & 3;
    int t = threadIdx.x;
    const int* irow = main_idx + (size_t)bm * WMn + ch * 16;
    const int* mrow = mmask + (size_t)bm * WMn + ch * 16;
    float4 acc = make_float4(-INF_VAL, -INF_VAL, -INF_VAL, -INF_VAL);
    #pragma unroll
    for (int w = 0; w < 16; ++w) {
        if (mrow[w] != 0) continue;
        float4 x = ((const float4*)(emb + (size_t)irow[w] * Dn))[t];
        fmax4(acc, x);
    }
    ((float4*)(partM + (size_t)blk * Dn))[t] = acc;
}

// user pool stage1 = one user per block
__global__ __launch_bounds__(192)
void pool_user_s1(const int* __restrict__ user_idx, const int* __restrict__ umask,
                  const float* __restrict__ emb, float* __restrict__ partU) {
    int bu = blockIdx.x;           // [B*U]
    int t = threadIdx.x;
    const int* irow = user_idx + (size_t)bu * WUn;
    const int* mrow = umask + (size_t)bu * WUn;
    float4 acc = make_float4(-INF_VAL, -INF_VAL, -INF_VAL, -INF_VAL);
    #pragma unroll
    for (int w = 0; w < WUn; ++w) {
        if (mrow[w] != 0) continue;
        float4 x = ((const float4*)(emb + (size_t)irow[w] * Dn))[t];
        fmax4(acc, x);
    }
    ((float4*)(partU + (size_t)bu * Dn))[t] = acc;
}

// combined stage2: blocks 0..31 = main, 32..47 = user
__global__ __launch_bounds__(192)
void pool_s2(const float* __restrict__ partM, const float* __restrict__ partU,
             float* __restrict__ outM, float* __restrict__ outU) {
    int blk = blockIdx.x;
    int t = threadIdx.x;
    float4 acc = make_float4(-INF_VAL, -INF_VAL, -INF_VAL, -INF_VAL);
    float* dst;
    if (blk < 32) {
        #pragma unroll
        for (int c = 0; c < 4; ++c) {
            float4 x = ((const float4*)(partM + (size_t)(blk * 4 + c) * Dn))[t];
            fmax4(acc, x);
        }
        dst = outM + (size_t)blk * Dn;
    } else {
        int b = blk - 32;
        for (int u2 = 0; u2 < Un; ++u2) {
            float4 x = ((const float4*)(partU + (size_t)(b * Un + u2) * Dn))[t];
            fmax4(acc, x);
        }
        dst = outU + (size_t)b * Dn;
    }
    if (acc.x == -INF_VAL) acc.x = 0.f;
    if (acc.y == -INF_VAL) acc.y = 0.f;
    if (acc.z == -INF_VAL) acc.z = 0.f;
    if (acc.w == -INF_VAL) acc.w = 0.f;
    ((float4*)dst)[t] = acc;
}

// ---------------------------------------------------------------------------
// Fused adj softmax + rowsum + column partial sums (single read of adj).
// grid = B*32 blocks, 512 threads; each block does 16 rows of one batch.
__global__ __launch_bounds__(512)
void adjsm_colsum_kernel(const float* __restrict__ adj, float* __restrict__ adjsm,
                         float* __restrict__ colsum, float* __restrict__ rowsum) {
    int blk = blockIdx.x;
    int b = blk >> 5, rc = blk & 31;
    int t = threadIdx.x;
    const float* base = adj + ((size_t)b * Sn + rc * 16) * Sn;
    float* obase = adjsm + ((size_t)b * Sn + rc * 16) * Sn;
    const float EM1 = 0.36787944117144233f;   // exp(-1)
    const float EP1 = 2.718281828459045f;     // exp(+1)
    __shared__ float red[8];
    float colacc = 0.f;
    for (int r = 0; r < 16; ++r) {
        float a = base[(size_t)r * Sn + t];
        colacc += a;
        float s = a;
        #pragma unroll
        for (int off = 32; off > 0; off >>= 1) s += __shfl_down(s, off, 64);
        if ((t & 63) == 0) red[t >> 6] = s;
        __syncthreads();
        float n1 = red[0] + red[1] + red[2] + red[3]
                 + red[4] + red[5] + red[6] + red[7];
        // softmax over {0,1} row: max = (n1>0)?1:0
        float e1, e0;
        if (n1 > 0.f) { e1 = 1.f; e0 = EM1; } else { e1 = EP1; e0 = 1.f; }
        float denom = n1 * e1 + (512.f - n1) * e0;
        float inv = 1.f / denom;
        obase[(size_t)r * Sn + t] = (a == 1.f ? e1 : e0) * inv;
        if (t == 0) rowsum[(size_t)b * Sn + rc * 16 + r] = n1;
        __syncthreads();   // protect red before next row
    }
    atomicAdd(&colsum[(size_t)b * Sn + t], colacc);
}

// mask[b,s] = (rowsum+colsum == 0)
__global__ __launch_bounds__(512)
void mask_kernel(const float* __restrict__ rowsum, const float* __restrict__ colsum,
                 float* __restrict__ maskout) {
    int i = blockIdx.x * 512 + threadIdx.x;
    maskout[i] = ((rowsum[i] + colsum[i]) == 0.f) ? 1.f : 0.f;
}

// transpose bf16 g -> gT[b][d][s]
__global__ __launch_bounds__(256)
void transpose_g(const ushort* __restrict__ gbf, ushort* __restrict__ gT) {
    __shared__ ushort tile[32][33];
    int b = blockIdx.z;
    int d0 = blockIdx.x * 32, s0 = blockIdx.y * 32;
    int tx = threadIdx.x & 31, ty = threadIdx.x >> 5;
    #pragma unroll
    for (int i = 0; i < 4; ++i)
        tile[ty + i * 8][tx] = gbf[((size_t)(b * Sn + s0 + ty + i * 8)) * Dn + d0 + tx];
    __syncthreads();
    #pragma unroll
    for (int i = 0; i < 4; ++i)
        gT[((size_t)(b * Dn + d0 + ty + i * 8)) * Sn + s0 + tx] = tile[tx][ty + i * 8];
}

// ---------------------------------------------------------------------------
// bf16 MFMA GEMM: C[m][n] = sum_k A[m][k]*B[n][k] (+bias[n])
// 128x128 tile, BK=64, 256 threads = 4 waves (2x2), 16x16x32 MFMA.
// SPLITC: bf16 output split at n=768 into Cout/Cout2 (wave-uniform branch).
template<int OUT_BF16, int HASBIAS, int SPLITC>
__global__ __launch_bounds__(256)
void gemm_mfma(const ushort* __restrict__ A, const ushort* __restrict__ B,
               const float* __restrict__ bias, void* __restrict__ Cout,
               void* __restrict__ Cout2,
               int Km, int lda, int ldb, int ldc,
               long long sA, long long sB, long long sC) {
    __shared__ ushort As[128 * 64];
    __shared__ ushort Bs[128 * 64];
    const ushort* Ab = A + (size_t)blockIdx.z * sA;
    const ushort* Bb = B + (size_t)blockIdx.z * sB;
    int i0 = blockIdx.y * 128, j0 = blockIdx.x * 128;
    int tid = threadIdx.x;
    int lane = tid & 63, wv = tid >> 6;
    int wr = wv >> 1, wc = wv & 1;
    int ln15 = lane & 15, lkg = lane >> 4;
    int sub = lane >> 3;
    int c8  = lane & 7;

    f32x4 acc[4][4] = {};

    for (int k0 = 0; k0 < Km; k0 += 64) {
        #pragma unroll
        for (int it = 0; it < 4; ++it) {
            int r = it * 32 + wv * 8 + sub;
            int cc = c8 ^ (r & 7);
            ushort* dstA = As + (it * 4096 + wv * 1024) / 2;
            ushort* dstB = Bs + (it * 4096 + wv * 1024) / 2;
            gload16(Ab + (size_t)(i0 + r) * lda + k0 + cc * 8, dstA);
            gload16(Bb + (size_t)(j0 + r) * ldb + k0 + cc * 8, dstB);
        }
        __syncthreads();
        #pragma unroll
        for (int kh = 0; kh < 2; ++kh) {
            short8 af[4], bfr[4];
            int kc = kh * 4 + lkg;
            #pragma unroll
            for (int f = 0; f < 4; ++f) {
                int ra = wr * 64 + f * 16 + ln15;
                af[f] = *(const short8*)((const char*)As + ra * 128 + ((kc ^ (ra & 7)) << 4));
                int rb = wc * 64 + f * 16 + ln15;
                bfr[f] = *(const short8*)((const char*)Bs + rb * 128 + ((kc ^ (rb & 7)) << 4));
            }
            #pragma unroll
            for (int fa = 0; fa < 4; ++fa)
                #pragma unroll
                for (int fb = 0; fb < 4; ++fb)
                    acc[fa][fb] = __builtin_amdgcn_mfma_f32_16x16x32_bf16(
                        af[fa], bfr[fb], acc[fa][fb], 0, 0, 0);
        }
        __syncthreads();
    }

    #pragma unroll
    for (int fa = 0; fa < 4; ++fa) {
        #pragma unroll
        for (int fb = 0; fb < 4; ++fb) {
            int n = j0 + wc * 64 + fb * 16 + ln15;
            float bv = HASBIAS ? bias[n] : 0.0f;
            #pragma unroll
            for (int rr = 0; rr < 4; ++rr) {
                int m = i0 + wr * 64 + fa * 16 + lkg * 4 + rr;
                float val = acc[fa][fb][rr] + bv;
                if (SPLITC) {
                    ushort* dst = (n < Dn) ? (ushort*)Cout : (ushort*)Cout2;
                    int nn = (n < Dn) ? n : n - Dn;
                    dst[(size_t)m * ldc + nn] = f2bf(val);
                } else if (OUT_BF16) {
                    ((ushort*)Cout)[(size_t)blockIdx.z * sC + (size_t)m * ldc + n] = f2bf(val);
                } else {
                    ((float*)Cout)[(size_t)blockIdx.z * sC + (size_t)m * ldc + n] = val;
                }
            }
        }
    }
}

// ---------------------------------------------------------------------------
// scores fixup + row softmax. Overrides masked rows/cols with exact rank-1 values.
__global__ __launch_bounds__(256)
void softmax_fix(float* __restrict__ dense, const int* __restrict__ flags,
                 const float* __restrict__ qs, const float* __restrict__ kq,
                 const double* __restrict__ consts, ushort* __restrict__ densebf) {
    int bs = blockIdx.x;
    int b = bs >> 9;
    int t = threadIdx.x;
    float* row = dense + (size_t)bs * 512;
    int f0 = flags[(b << 9) + t];
    int f1 = flags[(b << 9) + t + 256];
    bool sm = flags[bs] != 0;
    float x0, x1;
    if (sm) {
        float c1i = (float)consts[1] * INV_SQRT_D;
        x0 = f0 ? c1i : qs[(b << 9) + t] * INV_SQRT_D;
        x1 = f1 ? c1i : qs[(b << 9) + t + 256] * INV_SQRT_D;
    } else {
        float kqi = kq[bs] * INV_SQRT_D;
        x0 = f0 ? kqi : row[t] * INV_SQRT_D;
        x1 = f1 ? kqi : row[t + 256] * INV_SQRT_D;
    }
    float m = fmaxf(x0, x1);
    #pragma unroll
    for (int off = 32; off > 0; off >>= 1) m = fmaxf(m, __shfl_down(m, off, 64));
    __shared__ float red[4];
    __shared__ float bmax, bsum;
    if ((t & 63) == 0) red[t >> 6] = m;
    __syncthreads();
    if (t == 0) bmax = fmaxf(fmaxf(red[0], red[1]), fmaxf(red[2], red[3]));
    __syncthreads();
    float mx = bmax;
    float e0 = expf(x0 - mx), e1 = expf(x1 - mx);
    float s = e0 + e1;
    #pragma unroll
    for (int off = 32; off > 0; off >>= 1) s += __shfl_down(s, off, 64);
    if ((t & 63) == 0) red[t >> 6] = s;
    __syncthreads();
    if (t == 0) bsum = red[0] + red[1] + red[2] + red[3];
    __syncthreads();
    float inv = 1.f / bsum;
    float p0 = e0 * inv, p1 = e1 * inv;
    row[t] = p0; row[t + 256] = p1;
    ushort* bro = densebf + (size_t)bs * 512;
    bro[t] = f2bf(p0); bro[t + 256] = f2bf(p1);
}

// ---------------------------------------------------------------------------
extern "C" void kernel_launch(void* const* d_in, const int* in_sizes, int n_in,
                              void* d_out, int out_size, void* d_ws, size_t ws_size,
                              hipStream_t stream) {
    const int*   words     = (const int*)d_in[0];
    const int*   masks     = (const int*)d_in[1];
    const int*   main_idx  = (const int*)d_in[2];
    const int*   main_mask = (const int*)d_in[3];
    const int*   user_idx  = (const int*)d_in[4];
    const int*   user_mask = (const int*)d_in[5];
    const float* adj       = (const float*)d_in[6];
    const float* emb       = (const float*)d_in[7];
    const float* K_w       = (const float*)d_in[8];
    const float* K_b       = (const float*)d_in[9];
    const float* Q_w       = (const float*)d_in[10];
    const float* Q_b       = (const float*)d_in[11];

    float* out = (float*)d_out;
    char*  ws8 = (char*)d_ws;

    ushort* gbf    = (ushort*)(ws8 + WSB_GBF);
    ushort* gT     = (ushort*)(ws8 + WSB_GT);
    double* kbar   = (double*)(ws8 + WSB_KBAR);
    double* qbar   = (double*)(ws8 + WSB_QBAR);
    double* u      = (double*)(ws8 + WSB_U);
    double* v      = (double*)(ws8 + WSB_V);
    double* consts = (double*)(ws8 + WSB_CONSTS);
    float*  qs     = (float*)(ws8 + WSB_QS);
    float*  kq     = (float*)(ws8 + WSB_KQ);
    float*  colsum = (float*)(ws8 + WSB_COLSUM);
    int*    flags  = (int*)(ws8 + WSB_FLAGS);
    float*  rowsum = (float*)(ws8 + WSB_FLAGS);   // alias; flags dead by then

    // scratch parked in output regions (all fully rewritten later each call)
    char*   adjsc   = (char*)(out + OFF_ADJ);
    ushort* densebf = (ushort*)(adjsc + ADJB_DENSEBF);
    float*  partU   = (float*)(adjsc + ADJB_PARTU);
    float*  partM   = (float*)(adjsc + ADJB_PARTM);
    double* uvu     = (double*)(adjsc + ADJB_UVU);
    double* uvv     = (double*)(adjsc + ADJB_UVV);
    float*  bcat    = (float*)(adjsc + ADJB_BCAT);

    ushort* Kwb     = (ushort*)(out + OFF_DENSE);              // dead before scores GEMM
    ushort* Qwb     = Kwb + (size_t)Dn * Dn;                   // contiguous with Kwb
    ushort* keybf   = (ushort*)(out + OFF_GCN);                // dead before gcn GEMM
    ushort* querybf = keybf + (size_t)Bn * Sn * Dn;
    float*  dense   = out + OFF_DENSE;

    // weight folds (batch-independent)
    bar_kernel<<<Dn, 64, 0, stream>>>(K_w, K_b, Q_w, Q_b, kbar, qbar);
    uv_part<<<dim3(Dn / 64, 8), 64, 0, stream>>>(K_w, Q_w, kbar, qbar, uvu, uvv);
    uvred_consts<<<13, 64, 0, stream>>>(uvu, uvv, kbar, qbar, K_b, Q_b, u, v, consts);
    cvt2_bf16<<<dim3(Dn * Dn / 1024, 2), 256, 0, stream>>>(K_w, Q_w, Kwb, Qwb);
    misc_init<<<32, 256, 0, stream>>>(K_b, Q_b, bcat, colsum);

    // pools (parallel stages)
    pool_g_kernel<<<Bn * Sn, 192, 0, stream>>>(words, masks, emb, u, v, consts,
                                               gbf, qs, kq, flags);
    pool_main_s1<<<Bn * Mn_ * 4, 192, 0, stream>>>(main_idx, main_mask, emb, partM);
    pool_user_s1<<<Bn * Un, 192, 0, stream>>>(user_idx, user_mask, emb, partU);
    pool_s2<<<48, 192, 0, stream>>>(partM, partU, out + OFF_MAIN, out + OFF_USER);

    transpose_g<<<dim3(Dn / 32, Sn / 32, Bn), 256, 0, stream>>>(gbf, gT);

    // [key||query] = g @ [K_w||Q_w]^T + [K_b||Q_b]  (one fused dispatch, split out)
    gemm_mfma<1, 1, 1><<<dim3(2 * Dn / 128, (Bn * Sn) / 128, 1), 256, 0, stream>>>(
        gbf, Kwb, bcat, keybf, querybf, Dn, Dn, Dn, Dn, 0, 0, 0);

    // raw scores[b] = key[b] @ query[b]^T (f32 out, scale applied in softmax)
    gemm_mfma<0, 0, 0><<<dim3(Sn / 128, Sn / 128, Bn), 256, 0, stream>>>(
        keybf, querybf, nullptr, dense, nullptr, Dn, Dn, Dn, Sn,
        (long long)Sn * Dn, (long long)Sn * Dn, (long long)Sn * Sn);

    // fixup masked rows/cols + softmax; writes f32 dense + bf16 copy
    softmax_fix<<<Bn * Sn, 256, 0, stream>>>(dense, flags, qs, kq, consts, densebf);

    // gcn[b] = P[b] @ g[b] = densebf @ gT^T (f32 out)
    gemm_mfma<0, 0, 0><<<dim3(Dn / 128, Sn / 128, Bn), 256, 0, stream>>>(
        densebf, gT, nullptr, out + OFF_GCN, nullptr, Sn, Sn, Sn, Dn,
        (long long)Sn * Sn, (long long)Dn * Sn, (long long)Sn * Dn);

    // fused adj softmax + rowsum + colsum partials (single adj read), then mask
    adjsm_colsum_kernel<<<Bn * 32, 512, 0, stream>>>(adj, out + OFF_ADJ, colsum, rowsum);
    mask_kernel<<<Bn, 512, 0, stream>>>(rowsum, colsum, out + OFF_MASK);
}